// Round 5
// baseline (1282.580 us; speedup 1.0000x reference)
//
#include <hip/hip_runtime.h>

typedef _Float16 half8 __attribute__((ext_vector_type(8)));
typedef _Float16 half4 __attribute__((ext_vector_type(4)));
typedef float f32x4 __attribute__((ext_vector_type(4)));

__device__ __forceinline__ void gload_lds16(const void* g, void* l) {
  __builtin_amdgcn_global_load_lds((const __attribute__((address_space(1))) void*)g,
                                   (__attribute__((address_space(3))) void*)l, 16, 0, 0);
}

// ---------------- BN partial sums: grid 128 = (seg<<4 | c) ----------------
__global__ __launch_bounds__(256) void k_bn_partial(const float* __restrict__ x,
                                                    float* __restrict__ part) {
  const int c = blockIdx.x & 15;
  const int seg = blockIdx.x >> 4;
  const int t = threadIdx.x;
  float s = 0.f, s2 = 0.f;
  for (int b = 0; b < 32; ++b) {
    const float* row = x + (size_t)(b * 16 + c) * 4000 + seg * 500;
    for (int v = t; v < 500; v += 256) {
      float val = row[v];
      s += val;
      s2 += val * val;
    }
  }
#pragma unroll
  for (int off = 32; off > 0; off >>= 1) {
    s += __shfl_down(s, off);
    s2 += __shfl_down(s2, off);
  }
  __shared__ float rs_[4], rs2_[4];
  if ((t & 63) == 0) { rs_[t >> 6] = s; rs2_[t >> 6] = s2; }
  __syncthreads();
  if (t == 0) {
    part[c * 8 + seg] = rs_[0] + rs_[1] + rs_[2] + rs_[3];
    part[128 + c * 8 + seg] = rs2_[0] + rs2_[1] + rs2_[2] + rs2_[3];
  }
}

// ---------------- BN finalize ----------------
__global__ void k_bn_final(const float* __restrict__ part, float* __restrict__ musig) {
  const int c = threadIdx.x;
  if (c < 16) {
    float S = 0.f, S2 = 0.f;
#pragma unroll
    for (int seg = 0; seg < 8; ++seg) {
      S += part[c * 8 + seg];
      S2 += part[128 + c * 8 + seg];
    }
    const float inv = 1.f / 128000.f;
    float mu = S * inv;
    float var = S2 * inv - mu * mu;
    musig[c] = mu;
    musig[16 + c] = rsqrtf(var + 1e-5f);
  }
}

// ---------------- build x0 ----------------
__global__ __launch_bounds__(256) void k_build_x0(const float* __restrict__ x,
                                                  const int* __restrict__ perm,
                                                  const float* __restrict__ musig,
                                                  _Float16* __restrict__ X0) {
  const int idx = blockIdx.x * 256 + threadIdx.x;
  const int v = idx & 4095;
  const int m = idx >> 12;
  const int b = m & 31;
  const int c = m >> 5;
  const int pv = perm[v];
  float val = 0.f;
  if (pv < 4000)
    val = (x[((size_t)(b * 16 + c)) * 4000 + pv] - musig[c]) * musig[16 + c] * 0.0625f;
  X0[idx] = (_Float16)val;
}

// ---------------- f32 -> f16 convert ----------------
__global__ __launch_bounds__(256) void k_cvt_f16(const float* __restrict__ s,
                                                 _Float16* __restrict__ d, int n) {
  const int i = (blockIdx.x * 256 + threadIdx.x) * 4;
  if (i >= n) return;
  f32x4 v = *(const f32x4*)(s + i);
  half4 h;
  h[0] = (_Float16)v[0]; h[1] = (_Float16)v[1];
  h[2] = (_Float16)v[2]; h[3] = (_Float16)v[3];
  *(half4*)(d + i) = h;
}

// ---------------- zero fill (half8 granular) ----------------
__global__ __launch_bounds__(256) void k_zero(_Float16* __restrict__ p, int n8) {
  const int i = blockIdx.x * 256 + threadIdx.x;
  if (i < n8) *(half8*)(p + (size_t)i * 8) = half8{};
}

// ---------------- W permute+pad: Wp[f][k*CS + c] = W[f][c*25 + k] ----------------
__global__ __launch_bounds__(256) void k_prep_w(const float* __restrict__ W,
                                                _Float16* __restrict__ Wp,
                                                int F, int shiftC, int kround) {
  const int idx = blockIdx.x * 256 + threadIdx.x;
  const int CS = 1 << shiftC;
  const int KPtot = kround * CS;
  if (idx >= F * KPtot) return;
  const int f = idx / KPtot;
  const int rem = idx - f * KPtot;
  const int k = rem >> shiftC;
  const int c = rem & (CS - 1);
  float v = 0.f;
  if (k < 25) v = W[(size_t)f * (CS * 25) + c * 25 + k];
  Wp[idx] = (_Float16)v;
}

// ---------------- Chebyshev conv1 partial GEMM, cross-block K-split-8 ----------------
// P[kq][m][v] = sum_{u in kq-slice(512)} Xprev[m][u] * L[v][u]
// Block tile 256m x 256v. 512 thr = 8 waves (2m x 4v), wave 128x64 (8x4 frags).
// bid = by<<7 | kq<<4 | bx : XCD = bid&7 = bx&7 -> 4MB L-slice per XCD L2.
__global__ __launch_bounds__(512, 1) void k_cheb_ks(const _Float16* __restrict__ Xprev,
                                                    const _Float16* __restrict__ Lm,
                                                    _Float16* __restrict__ P) {
  __shared__ _Float16 lds[2][32768];  // [buf][A:256x64 | B:256x64] = 128 KB
  const int t = threadIdx.x;
  const int lane = t & 63;
  const int g = lane >> 4;
  const int w = t >> 6;
  const int wm = w >> 2, wn = w & 3;
  const int bid = blockIdx.x;
  const int bx = bid & 15;
  const int kq = (bid >> 4) & 7;
  const int by = bid >> 7;
  const int v0 = bx * 256, m0 = by * 256;
  const size_t rs = 8192;  // 4096 * 2B

  const char* Ag = (const char*)Xprev + (size_t)m0 * rs + (size_t)kq * 1024;
  const char* Bg = (const char*)Lm + (size_t)v0 * rs + (size_t)kq * 1024;

  f32x4 acc[8][4] = {};

  auto stage = [&](int buf, int tt) {  // 8 gload_lds per thread (A4 + B4)
    char* A = (char*)&lds[buf][0];
    char* B = (char*)&lds[buf][16384];
#pragma unroll
    for (int j = 0; j < 4; ++j) {
      const int ch = j * 512 + t;
      const int row = ch >> 3, c8 = ch & 7;
      gload_lds16(Ag + (size_t)row * rs + tt * 128 + ((c8 ^ (row & 7)) << 4), A + ch * 16);
    }
#pragma unroll
    for (int j = 0; j < 4; ++j) {
      const int ch = j * 512 + t;
      const int row = ch >> 3, c8 = ch & 7;
      gload_lds16(Bg + (size_t)row * rs + tt * 128 + ((c8 ^ (row & 7)) << 4), B + ch * 16);
    }
  };

  stage(0, 0);

  for (int tt = 0; tt < 8; ++tt) {
    const int cur = tt & 1;
    if (tt + 1 < 8) {
      stage(cur ^ 1, tt + 1);
      asm volatile("s_waitcnt vmcnt(8)" ::: "memory");  // own stage(tt) landed
    } else {
      asm volatile("s_waitcnt vmcnt(0)" ::: "memory");
    }
    asm volatile("s_barrier" ::: "memory");
    const char* A = (const char*)&lds[cur][0];
    const char* B = (const char*)&lds[cur][16384];
#pragma unroll
    for (int kk = 0; kk < 2; ++kk) {
      const int cb = kk * 64 + (g << 4);
      half8 a[8], b[4];
#pragma unroll
      for (int mi = 0; mi < 8; ++mi) {
        const int ar = wm * 128 + mi * 16 + (lane & 15);
        a[mi] = *(const half8*)(A + ar * 128 + (cb ^ ((ar & 7) << 4)));
      }
#pragma unroll
      for (int ni = 0; ni < 4; ++ni) {
        const int br = wn * 64 + ni * 16 + (lane & 15);
        b[ni] = *(const half8*)(B + br * 128 + (cb ^ ((br & 7) << 4)));
      }
#pragma unroll
      for (int mi = 0; mi < 8; ++mi)
#pragma unroll
        for (int ni = 0; ni < 4; ++ni)
          acc[mi][ni] = __builtin_amdgcn_mfma_f32_16x16x32_f16(a[mi], b[ni], acc[mi][ni], 0, 0, 0);
    }
    asm volatile("s_barrier" ::: "memory");
  }

  _Float16* Pq = P + (size_t)kq * 2097152;
  const int rb = g << 2;
#pragma unroll
  for (int mi = 0; mi < 8; ++mi) {
#pragma unroll
    for (int ni = 0; ni < 4; ++ni) {
      const int vv = v0 + wn * 64 + ni * 16 + (lane & 15);
#pragma unroll
      for (int r = 0; r < 4; ++r) {
        const int mm = m0 + wm * 128 + mi * 16 + rb + r;
        Pq[(size_t)mm * 4096 + vv] = (_Float16)acc[mi][ni][r];
      }
    }
  }
}

// ---------------- reduce 8 partials: Xout = alpha*sum(P) - beta*Xm2 ----------------
__global__ __launch_bounds__(256) void k_cheb_red(const _Float16* __restrict__ P,
                                                  const _Float16* __restrict__ Xm2,
                                                  _Float16* __restrict__ Xout,
                                                  float alpha, float beta) {
  const size_t i = ((size_t)blockIdx.x * 256 + threadIdx.x) * 8;
  float s[8] = {};
#pragma unroll
  for (int p = 0; p < 8; ++p) {
    half8 v = *(const half8*)(P + (size_t)p * 2097152 + i);
#pragma unroll
    for (int j = 0; j < 8; ++j) s[j] += (float)v[j];
  }
  half8 xm2 = {};
  if (beta != 0.f) xm2 = *(const half8*)(Xm2 + i);
  half8 o;
#pragma unroll
  for (int j = 0; j < 8; ++j) o[j] = (_Float16)(alpha * s[j] - beta * (float)xm2[j]);
  *(half8*)(Xout + i) = o;
}

// ---------------- Chebyshev conv2 GEMM (in-block K-split-2, unchanged R3) ----------------
__global__ __launch_bounds__(512, 2) void k_cheb(const _Float16* __restrict__ Xprev,
                                                 const _Float16* __restrict__ Lm,
                                                 const _Float16* __restrict__ Xm2,
                                                 _Float16* __restrict__ Xout,
                                                 int V, float alpha, float beta) {
  __shared__ _Float16 lds[2][2][12288];
  const int t = threadIdx.x;
  const int lane = t & 63;
  const int w = t >> 6;
  const int kh = w >> 2;
  const int wl = w & 3;
  const int wr = wl >> 1, wc = wl & 1;
  const int v0 = blockIdx.x * 64;
  const int m0 = blockIdx.y * 128;
  const size_t rs = (size_t)V * 2;
  const int K2 = V >> 1;
  const int NT2 = K2 >> 6;

  const char* Ag = (const char*)Xprev + (size_t)m0 * rs + (size_t)kh * K2 * 2;
  const char* Bg = (const char*)Lm + (size_t)v0 * rs + (size_t)kh * K2 * 2;
  const size_t soff = (size_t)(lane >> 3) * rs + (size_t)(((lane & 7) * 16) ^ ((lane >> 3) << 4));

  f32x4 acc[4][2] = {};

  auto stage = [&](int buf, int tt) {
    const char* ag = Ag + (size_t)tt * 128 + soff;
    const char* bg = Bg + (size_t)tt * 128 + soff;
    char* A = (char*)&lds[kh][buf][0];
    char* B = (char*)&lds[kh][buf][8192];
#pragma unroll
    for (int j = 0; j < 4; ++j) {
      const int r0 = wl * 32 + j * 8;
      gload_lds16(ag + (size_t)r0 * rs, A + r0 * 128);
    }
#pragma unroll
    for (int j = 0; j < 2; ++j) {
      const int r0 = wl * 16 + j * 8;
      gload_lds16(bg + (size_t)r0 * rs, B + r0 * 128);
    }
  };

  stage(0, 0);

  for (int tt = 0; tt < NT2; ++tt) {
    const int cur = tt & 1;
    if (tt + 1 < NT2) {
      stage(cur ^ 1, tt + 1);
      asm volatile("s_waitcnt vmcnt(6)" ::: "memory");
    } else {
      asm volatile("s_waitcnt vmcnt(0)" ::: "memory");
    }
    asm volatile("s_barrier" ::: "memory");
    const char* A = (const char*)&lds[kh][cur][0];
    const char* B = (const char*)&lds[kh][cur][8192];
#pragma unroll
    for (int kk = 0; kk < 2; ++kk) {
      const int cb = kk * 64 + ((lane >> 4) << 4);
      half8 a[4], b[2];
#pragma unroll
      for (int mi = 0; mi < 4; ++mi) {
        const int ar = wr * 64 + mi * 16 + (lane & 15);
        a[mi] = *(const half8*)(A + ar * 128 + (cb ^ ((ar & 7) << 4)));
      }
#pragma unroll
      for (int ni = 0; ni < 2; ++ni) {
        const int br = wc * 32 + ni * 16 + (lane & 15);
        b[ni] = *(const half8*)(B + br * 128 + (cb ^ ((br & 7) << 4)));
      }
#pragma unroll
      for (int mi = 0; mi < 4; ++mi)
#pragma unroll
        for (int ni = 0; ni < 2; ++ni)
          acc[mi][ni] = __builtin_amdgcn_mfma_f32_16x16x32_f16(a[mi], b[ni], acc[mi][ni], 0, 0, 0);
    }
    asm volatile("s_barrier" ::: "memory");
  }

  __syncthreads();
  float* red = (float*)&lds[0][0][0];
  if (kh == 1) {
    float* dst = red + wl * 2048 + lane * 4;
#pragma unroll
    for (int mi = 0; mi < 4; ++mi)
#pragma unroll
      for (int ni = 0; ni < 2; ++ni)
        *(f32x4*)(dst + (mi * 2 + ni) * 256) = acc[mi][ni];
  }
  __syncthreads();
  if (kh == 0) {
    const float* src = red + wl * 2048 + lane * 4;
    const int rbase = (lane >> 4) << 2;
#pragma unroll
    for (int mi = 0; mi < 4; ++mi) {
#pragma unroll
      for (int ni = 0; ni < 2; ++ni) {
        f32x4 o = *(const f32x4*)(src + (mi * 2 + ni) * 256);
        const int vv = v0 + wc * 32 + ni * 16 + (lane & 15);
#pragma unroll
        for (int r = 0; r < 4; ++r) {
          const int mm = m0 + wr * 64 + mi * 16 + rbase + r;
          const size_t idx = (size_t)mm * V + vv;
          float val = alpha * (acc[mi][ni][r] + o[r]);
          if (beta != 0.f) val -= (float)Xm2[idx];
          Xout[idx] = (_Float16)val;
        }
      }
    }
  }
}

// ---------------- Dense projection GEMM, gload_lds + counted vmcnt ----------------
// Yt[f][n] = relu(ascale * sum_q Wp[f][q]*B[q][n] + bscale*bias[f])
// B[q][n] = XS[k][(c*32+b)*Vv + v], q = k<<shiftC | c, n = b*Vv + v.
// Block: FT f x 64 n; 4 waves, wave tile FT x 16. BK=64, dbuf.
// A LDS [FT][64] linear + row-XOR swizzle (chunk ^ f&7), staged via gload_lds
// with pre-swizzled source. B LDS [64][64] linear + chunk-XOR (q>>3)&7.
// Zero-padding k>=25 comes from pre-zeroed XS planes 25..27.
template <int FT>
__global__ __launch_bounds__(256, 2) void k_dense(const _Float16* __restrict__ Wp,
                                                  const _Float16* __restrict__ XS,
                                                  const float* __restrict__ bias,
                                                  float* __restrict__ Yt,
                                                  int Vv, int shiftC, int nsteps,
                                                  int Ntot, float ascale, float bscale) {
  __shared__ _Float16 Alds[2][FT * 64];
  __shared__ _Float16 Blds[2][64 * 64];
  const int t = threadIdx.x;
  const int lane = t & 63;
  const int g = lane >> 4;
  const int w = t >> 6;
  const int n0 = blockIdx.x * 64;
  const int b = n0 / Vv;
  const int vb = n0 % Vv;
  const int Kp = nsteps * 64;
  const int cmask = (1 << shiftC) - 1;
  const size_t plane = 2097152;

  f32x4 acc[FT / 16] = {};

  auto stage = [&](int buf, int s) {
    const int q0 = s * 64;
    char* A = (char*)&Alds[buf][0];
    char* B = (char*)&Blds[buf][0];
#pragma unroll
    for (int j = 0; j < FT / 32; ++j) {  // A: FT*8 chunks
      const int ch = j * 256 + t;
      const int f = ch >> 3, c8 = ch & 7;
      gload_lds16((const char*)Wp + ((size_t)f * Kp + q0) * 2 + ((c8 ^ (f & 7)) << 4),
                  A + ch * 16);
    }
#pragma unroll
    for (int j = 0; j < 2; ++j) {  // B: 512 chunks
      const int ch = j * 256 + t;
      const int q = ch >> 3, c8 = ch & 7;
      const int qq = q0 + q;
      const int k = qq >> shiftC, c = qq & cmask;
      const int sz = (q >> 3) & 7;
      gload_lds16((const char*)XS + ((size_t)k * plane + (size_t)(c * 32 + b) * Vv + vb) * 2 +
                      ((c8 ^ sz) << 4),
                  B + ch * 16);
    }
  };

  stage(0, 0);

  for (int s = 0; s < nsteps; ++s) {
    const int cur = s & 1;
    if (s + 1 < nsteps) {
      stage(cur ^ 1, s + 1);
      if constexpr (FT == 64) {
        asm volatile("s_waitcnt vmcnt(4)" ::: "memory");
      } else {
        asm volatile("s_waitcnt vmcnt(6)" ::: "memory");
      }
    } else {
      asm volatile("s_waitcnt vmcnt(0)" ::: "memory");
    }
    asm volatile("s_barrier" ::: "memory");
    const _Float16* A = &Alds[cur][0];
    const _Float16* B = &Blds[cur][0];
#pragma unroll
    for (int kk = 0; kk < 2; ++kk) {
      half8 bf;
      const int c = lane & 15;
#pragma unroll
      for (int j = 0; j < 8; ++j) {
        const int q = kk * 32 + g * 8 + j;
        const int sz = (q >> 3) & 7;
        bf[j] = B[q * 64 + ((w * 16 + c) ^ (sz << 3))];
      }
#pragma unroll
      for (int mi = 0; mi < FT / 16; ++mi) {
        const int ar = mi * 16 + c;
        half8 af = *(const half8*)((const char*)A + ar * 128 +
                                   ((kk * 64 + g * 16) ^ ((ar & 7) << 4)));
        acc[mi] = __builtin_amdgcn_mfma_f32_16x16x32_f16(af, bf, acc[mi], 0, 0, 0);
      }
    }
    asm volatile("s_barrier" ::: "memory");
  }

  const int n = n0 + w * 16 + (lane & 15);
#pragma unroll
  for (int mi = 0; mi < FT / 16; ++mi) {
#pragma unroll
    for (int r = 0; r < 4; ++r) {
      const int f = mi * 16 + g * 4 + r;
      Yt[(size_t)f * Ntot + n] = fmaxf(ascale * acc[mi][r] + bscale * bias[f], 0.f);
    }
  }
}

// ---------------- pool1 ----------------
__global__ __launch_bounds__(256) void k_pool1(const float* __restrict__ Yt,
                                               _Float16* __restrict__ X2) {
  const int idx = blockIdx.x * 256 + threadIdx.x;
  const int v2 = idx & 1023;
  const int rest = idx >> 10;
  const int b = rest & 31;
  const int f = rest >> 5;
  f32x4 q = *(const f32x4*)(Yt + (size_t)f * 131072 + b * 4096 + v2 * 4);
  float mx = fmaxf(fmaxf(q[0], q[1]), fmaxf(q[2], q[3]));
  X2[(size_t)(f * 32 + b) * 1024 + v2] = (_Float16)(mx * 0.015625f);
}

// ---------------- pool2 ----------------
__global__ __launch_bounds__(256) void k_pool2(const float* __restrict__ Yt,
                                               float* __restrict__ p2) {
  const int idx = blockIdx.x * 256 + threadIdx.x;
  const int v3 = idx & 255;
  const int rest = idx >> 8;
  const int f = rest & 127;
  const int b = rest >> 7;
  f32x4 q = *(const f32x4*)(Yt + (size_t)f * 32768 + b * 1024 + v3 * 4);
  float mx = fmaxf(fmaxf(q[0], q[1]), fmaxf(q[2], q[3]));
  p2[(size_t)b * 32768 + f * 256 + v3] = mx;
}

// ---------------- FC pass 1 ----------------
__global__ __launch_bounds__(256) void k_fc_part(const float* __restrict__ p2,
                                                 const float* __restrict__ Wfc,
                                                 float* __restrict__ partF) {
  const int b = blockIdx.x >> 3;
  const int seg = blockIdx.x & 7;
  const int t = threadIdx.x;
  const int lane = t & 63;
  const int w = t >> 6;
  const int base = seg * 4096;
  float acc[10];
#pragma unroll
  for (int o = 0; o < 10; ++o) acc[o] = 0.f;
  const float* pb = p2 + (size_t)b * 32768 + base;
  for (int i = t; i < 4096; i += 256) {
    float p = pb[i];
#pragma unroll
    for (int o = 0; o < 10; ++o) acc[o] += p * Wfc[(size_t)o * 32768 + base + i];
  }
#pragma unroll
  for (int off = 32; off > 0; off >>= 1)
#pragma unroll
    for (int o = 0; o < 10; ++o) acc[o] += __shfl_down(acc[o], off);
  __shared__ float rws[10][4];
  if (lane == 0) {
#pragma unroll
    for (int o = 0; o < 10; ++o) rws[o][w] = acc[o];
  }
  __syncthreads();
  if (t < 10) partF[blockIdx.x * 10 + t] =
      rws[t][0] + rws[t][1] + rws[t][2] + rws[t][3];
}

// ---------------- FC pass 2 ----------------
__global__ void k_fc_final(const float* __restrict__ partF,
                           const float* __restrict__ bfc,
                           float* __restrict__ out) {
  const int t = threadIdx.x;
  if (t < 320) {
    const int b = t / 10, o = t - b * 10;
    float s = 0.f;
#pragma unroll
    for (int seg = 0; seg < 8; ++seg) s += partF[(b * 8 + seg) * 10 + o];
    out[b * 10 + o] = 64.f * s + bfc[o];
  }
}

extern "C" void kernel_launch(void* const* d_in, const int* in_sizes, int n_in,
                              void* d_out, int out_size, void* d_ws, size_t ws_size,
                              hipStream_t stream) {
  (void)in_sizes; (void)n_in; (void)out_size; (void)ws_size;
  const float* x = (const float*)d_in[0];
  const int* perm = (const int*)d_in[1];
  const float* L1 = (const float*)d_in[2];
  const float* L2 = (const float*)d_in[3];
  const float* W1 = (const float*)d_in[4];
  const float* b1 = (const float*)d_in[5];
  const float* W2 = (const float*)d_in[6];
  const float* b2 = (const float*)d_in[7];
  const float* Wfc = (const float*)d_in[8];
  const float* bfc = (const float*)d_in[9];
  float* out = (float*)d_out;

  char* ws = (char*)d_ws;
  size_t off = 0;
  auto alloc = [&](size_t bytes) {
    char* p = ws + off;
    off += (bytes + 255) & ~(size_t)255;
    return p;
  };
  _Float16* L1h = (_Float16*)alloc(16777216ull * 2);
  _Float16* L2h = (_Float16*)alloc(1048576ull * 2);
  _Float16* W1p = (_Float16*)alloc(64ull * 448 * 2);
  _Float16* W2p = (_Float16*)alloc(128ull * 1664 * 2);
  float* part = (float*)alloc(256 * 4);
  float* musig = (float*)alloc(32 * 4);
  float* partF = (float*)alloc(2560 * 4);
  _Float16* XS = (_Float16*)alloc(28ull * 2097152 * 2);   // 25 states + 3 zero planes
  float* Yt = (float*)alloc(64ull * 131072 * 4);          // 32MB; aliased as Pq during conv1
  float* p2 = (float*)alloc(32ull * 128 * 256 * 4);
  _Float16* Pq = (_Float16*)Yt;  // 8 partial planes (32MB) — dead before dense1 writes Yt

  const size_t plane = 2097152;

  k_cvt_f16<<<16384, 256, 0, stream>>>(L1, L1h, 16777216);
  k_cvt_f16<<<1024, 256, 0, stream>>>(L2, L2h, 1048576);
  k_prep_w<<<112, 256, 0, stream>>>(W1, W1p, 64, 4, 28);
  k_prep_w<<<832, 256, 0, stream>>>(W2, W2p, 128, 6, 26);
  k_zero<<<3072, 256, 0, stream>>>(XS + 25 * plane, 786432);  // zero planes 25..27
  k_bn_partial<<<128, 256, 0, stream>>>(x, part);
  k_bn_final<<<1, 64, 0, stream>>>(part, musig);
  k_build_x0<<<8192, 256, 0, stream>>>(x, perm, musig, XS);

  for (int k = 1; k < 25; ++k) {
    k_cheb_ks<<<256, 512, 0, stream>>>(XS + (size_t)(k - 1) * plane, L1h, Pq);
    k_cheb_red<<<1024, 256, 0, stream>>>(
        Pq, XS + (size_t)(k >= 2 ? k - 2 : 0) * plane, XS + (size_t)k * plane,
        (k == 1) ? 1.f : 2.f, (k == 1) ? 0.f : 1.f);
  }
  k_dense<64><<<dim3(2048, 1), 256, 0, stream>>>(W1p, XS, b1, Yt, 4096, 4, 7,
                                                 131072, 16.f, 1.f);
  k_pool1<<<8192, 256, 0, stream>>>(Yt, XS);
  for (int k = 1; k < 25; ++k) {
    k_cheb<<<dim3(16, 16), 512, 0, stream>>>(
        XS + (size_t)(k - 1) * plane, L2h,
        XS + (size_t)(k >= 2 ? k - 2 : 0) * plane, XS + (size_t)k * plane,
        1024, (k == 1) ? 1.f : 2.f, (k == 1) ? 0.f : 1.f);
  }
  k_dense<128><<<dim3(512, 1), 256, 0, stream>>>(W2p, XS, b2, Yt, 1024, 6, 26,
                                                 32768, 1.f, 0.015625f);
  k_pool2<<<4096, 256, 0, stream>>>(Yt, p2);
  k_fc_part<<<256, 256, 0, stream>>>(p2, Wfc, partF);
  k_fc_final<<<1, 320, 0, stream>>>(partF, bfc, out);
}

// Round 6
// 1248.183 us; speedup vs baseline: 1.0276x; 1.0276x over previous
//
#include <hip/hip_runtime.h>

typedef _Float16 half8 __attribute__((ext_vector_type(8)));
typedef _Float16 half4 __attribute__((ext_vector_type(4)));
typedef float f32x4 __attribute__((ext_vector_type(4)));

__device__ __forceinline__ void gload_lds16(const void* g, void* l) {
  __builtin_amdgcn_global_load_lds((const __attribute__((address_space(1))) void*)g,
                                   (__attribute__((address_space(3))) void*)l, 16, 0, 0);
}

// ---------------- BN partial sums: grid 128 = (seg<<4 | c) ----------------
__global__ __launch_bounds__(256) void k_bn_partial(const float* __restrict__ x,
                                                    float* __restrict__ part) {
  const int c = blockIdx.x & 15;
  const int seg = blockIdx.x >> 4;
  const int t = threadIdx.x;
  float s = 0.f, s2 = 0.f;
  for (int b = 0; b < 32; ++b) {
    const float* row = x + (size_t)(b * 16 + c) * 4000 + seg * 500;
    for (int v = t; v < 500; v += 256) {
      float val = row[v];
      s += val;
      s2 += val * val;
    }
  }
#pragma unroll
  for (int off = 32; off > 0; off >>= 1) {
    s += __shfl_down(s, off);
    s2 += __shfl_down(s2, off);
  }
  __shared__ float rs_[4], rs2_[4];
  if ((t & 63) == 0) { rs_[t >> 6] = s; rs2_[t >> 6] = s2; }
  __syncthreads();
  if (t == 0) {
    part[c * 8 + seg] = rs_[0] + rs_[1] + rs_[2] + rs_[3];
    part[128 + c * 8 + seg] = rs2_[0] + rs2_[1] + rs2_[2] + rs2_[3];
  }
}

// ---------------- BN finalize ----------------
__global__ void k_bn_final(const float* __restrict__ part, float* __restrict__ musig) {
  const int c = threadIdx.x;
  if (c < 16) {
    float S = 0.f, S2 = 0.f;
#pragma unroll
    for (int seg = 0; seg < 8; ++seg) {
      S += part[c * 8 + seg];
      S2 += part[128 + c * 8 + seg];
    }
    const float inv = 1.f / 128000.f;
    float mu = S * inv;
    float var = S2 * inv - mu * mu;
    musig[c] = mu;
    musig[16 + c] = rsqrtf(var + 1e-5f);
  }
}

// ---------------- build x0 (normalized, permuted, transposed, scaled 1/16) ----------------
__global__ __launch_bounds__(256) void k_build_x0(const float* __restrict__ x,
                                                  const int* __restrict__ perm,
                                                  const float* __restrict__ musig,
                                                  _Float16* __restrict__ X0) {
  const int idx = blockIdx.x * 256 + threadIdx.x;
  const int v = idx & 4095;
  const int m = idx >> 12;
  const int b = m & 31;
  const int c = m >> 5;
  const int pv = perm[v];
  float val = 0.f;
  if (pv < 4000)
    val = (x[((size_t)(b * 16 + c)) * 4000 + pv] - musig[c]) * musig[16 + c] * 0.0625f;
  X0[idx] = (_Float16)val;
}

// ---------------- f32 -> f16 convert ----------------
__global__ __launch_bounds__(256) void k_cvt_f16(const float* __restrict__ s,
                                                 _Float16* __restrict__ d, int n) {
  const int i = (blockIdx.x * 256 + threadIdx.x) * 4;
  if (i >= n) return;
  f32x4 v = *(const f32x4*)(s + i);
  half4 h;
  h[0] = (_Float16)v[0]; h[1] = (_Float16)v[1];
  h[2] = (_Float16)v[2]; h[3] = (_Float16)v[3];
  *(half4*)(d + i) = h;
}

// ---------------- zero fill ----------------
__global__ __launch_bounds__(256) void k_zero(_Float16* __restrict__ p, int n8) {
  const int i = blockIdx.x * 256 + threadIdx.x;
  if (i < n8) *(half8*)(p + (size_t)i * 8) = half8{};
}

// ---------------- W permute+pad: Wp[f][k*CS + c] = W[f][c*25 + k] ----------------
__global__ __launch_bounds__(256) void k_prep_w(const float* __restrict__ W,
                                                _Float16* __restrict__ Wp,
                                                int F, int shiftC, int kround) {
  const int idx = blockIdx.x * 256 + threadIdx.x;
  const int CS = 1 << shiftC;
  const int KPtot = kround * CS;
  if (idx >= F * KPtot) return;
  const int f = idx / KPtot;
  const int rem = idx - f * KPtot;
  const int k = rem >> shiftC;
  const int c = rem & (CS - 1);
  float v = 0.f;
  if (k < 25) v = W[(size_t)f * (CS * 25) + c * 25 + k];
  Wp[idx] = (_Float16)v;
}

// ---------------- Chebyshev partial GEMM, m201-style fine-phase pipeline ----------------
// P[kq][m][v] = sum_{u in kq K-slice} Xprev[m][u] * L[v][u]
// Tile 128m x 256v, BK=64. 512 thr = 8 waves (2m x 4v), wave 64x64 (4x4 frags).
// 3-buffer LDS rotation (48KB each), full-tile staging split in 2 half-stages
// (3 gload_lds/thread), issued 2 tiles ahead, one half per phase.
// Per phase: 8 ds_read frags | stage 3 | [vmcnt(6) once/tile] | barrier |
//            lgkmcnt(0)+sched_barrier | setprio(1) 16 MFMA setprio(0) | barrier.
// Staging: linear LDS dest + pre-swizzled global source; reads swizzled
// (byte ^ (row&7)<<4) -> 2-way banks (free). Verified conflict-free in R5.
__global__ __launch_bounds__(512, 2) void k_cheb8(const _Float16* __restrict__ Xprev,
                                                  const _Float16* __restrict__ Lm,
                                                  _Float16* __restrict__ P,
                                                  int V, int NT, int bxbits, int bybits) {
  __shared__ _Float16 lds[3][24576];  // [buf][A:128x64 (16KB) | B:256x64 (32KB)]
  const int t = threadIdx.x;
  const int lane = t & 63;
  const int ln = lane & 15;
  const int g = lane >> 4;
  const int g16 = g << 4;
  const int w = t >> 6;
  const int wm = w >> 2, wn = w & 3;
  const int bid = blockIdx.x;
  const int bx = bid & ((1 << bxbits) - 1);
  const int by = (bid >> bxbits) & ((1 << bybits) - 1);
  const int kq = bid >> (bxbits + bybits);
  const int v0 = bx * 256, m0 = by * 128;
  const size_t rs = (size_t)V * 2;
  const int koffB = kq * NT * 128;  // K byte offset of this slice

  const char* Ag = (const char*)Xprev + (size_t)m0 * rs + koffB;
  const char* Bg = (const char*)Lm + (size_t)v0 * rs + koffB;

  f32x4 acc[4][4] = {};

  auto stageHalf = [&](int buf, int tt, int half) {  // 3 gload_lds / thread
    char* Lb = (char*)&lds[buf][0];
#pragma unroll
    for (int j = 0; j < 3; ++j) {
      const int idx = half * 1536 + j * 512 + t;
      if (idx < 1024) {  // A chunks (wave-uniform branch: 64-aligned ranges)
        const int row = idx >> 3, c8 = idx & 7;
        gload_lds16(Ag + (size_t)row * rs + tt * 128 + ((c8 ^ (row & 7)) << 4),
                    Lb + idx * 16);
      } else {           // B chunks
        const int bi = idx - 1024;
        const int row = bi >> 3, c8 = bi & 7;
        gload_lds16(Bg + (size_t)row * rs + tt * 128 + ((c8 ^ (row & 7)) << 4),
                    Lb + 16384 + bi * 16);
      }
    }
  };

  // prologue: stage T0, T1 fully (12 loads); wait T0 (6 newest outstanding = T1)
  stageHalf(0, 0, 0); stageHalf(0, 0, 1);
  stageHalf(1, 1, 0); stageHalf(1, 1, 1);
  asm volatile("s_waitcnt vmcnt(6)" ::: "memory");
  asm volatile("s_barrier" ::: "memory");

  for (int tt = 0; tt < NT; ++tt) {
    const int cur = tt % 3;
    const int nxt = (tt + 2) % 3;
    const char* A = (const char*)&lds[cur][0];
    const char* B = A + 16384;
#pragma unroll
    for (int kk = 0; kk < 2; ++kk) {
      half8 a[4], b[4];
#pragma unroll
      for (int mi = 0; mi < 4; ++mi) {
        const int ar = wm * 64 + mi * 16 + ln;
        a[mi] = *(const half8*)(A + ar * 128 + ((kk * 64 + g16) ^ ((ar & 7) << 4)));
      }
#pragma unroll
      for (int ni = 0; ni < 4; ++ni) {
        const int br = wn * 64 + ni * 16 + ln;
        b[ni] = *(const half8*)(B + br * 128 + ((kk * 64 + g16) ^ ((br & 7) << 4)));
      }
      if (tt + 2 < NT) stageHalf(nxt, tt + 2, kk);
      if (kk == 1) {
        if (tt + 2 < NT) {
          asm volatile("s_waitcnt vmcnt(6)" ::: "memory");  // T(t+1) landed; T(t+2) in flight
        } else {
          asm volatile("s_waitcnt vmcnt(0)" ::: "memory");  // tail drain
        }
      }
      asm volatile("s_barrier" ::: "memory");
      asm volatile("s_waitcnt lgkmcnt(0)" ::: "memory");
      __builtin_amdgcn_sched_barrier(0);
      __builtin_amdgcn_s_setprio(1);
#pragma unroll
      for (int mi = 0; mi < 4; ++mi)
#pragma unroll
        for (int ni = 0; ni < 4; ++ni)
          acc[mi][ni] = __builtin_amdgcn_mfma_f32_16x16x32_f16(a[mi], b[ni], acc[mi][ni], 0, 0, 0);
      __builtin_amdgcn_s_setprio(0);
      asm volatile("s_barrier" ::: "memory");
    }
  }

  // epilogue: write fp16 partial plane (plane = 2097152 for both convs)
  _Float16* Pq = P + (size_t)kq * 2097152;
#pragma unroll
  for (int mi = 0; mi < 4; ++mi) {
#pragma unroll
    for (int ni = 0; ni < 4; ++ni) {
      const int vv = v0 + wn * 64 + ni * 16 + ln;
      const int mmb = m0 + wm * 64 + mi * 16 + g * 4;
#pragma unroll
      for (int r = 0; r < 4; ++r)
        Pq[(size_t)(mmb + r) * V + vv] = (_Float16)acc[mi][ni][r];
    }
  }
}

// ---------------- reduce 4 partials: Xout = alpha*(P0+..+P3) - beta*Xm2 ----------------
__global__ __launch_bounds__(256) void k_cheb_red4(const _Float16* __restrict__ P,
                                                   const _Float16* __restrict__ Xm2,
                                                   _Float16* __restrict__ Xout,
                                                   float alpha, float beta) {
  const size_t i = ((size_t)blockIdx.x * 256 + threadIdx.x) * 8;
  float s[8] = {};
#pragma unroll
  for (int p = 0; p < 4; ++p) {
    half8 v = *(const half8*)(P + (size_t)p * 2097152 + i);
#pragma unroll
    for (int j = 0; j < 8; ++j) s[j] += (float)v[j];
  }
  half8 xm2 = {};
  if (beta != 0.f) xm2 = *(const half8*)(Xm2 + i);
  half8 o;
#pragma unroll
  for (int j = 0; j < 8; ++j) o[j] = (_Float16)(alpha * s[j] - beta * (float)xm2[j]);
  *(half8*)(Xout + i) = o;
}

// ---------------- Dense projection GEMM, gload_lds + counted vmcnt (R5) ----------------
template <int FT>
__global__ __launch_bounds__(256, 2) void k_dense(const _Float16* __restrict__ Wp,
                                                  const _Float16* __restrict__ XS,
                                                  const float* __restrict__ bias,
                                                  float* __restrict__ Yt,
                                                  int Vv, int shiftC, int nsteps,
                                                  int Ntot, float ascale, float bscale) {
  __shared__ _Float16 Alds[2][FT * 64];
  __shared__ _Float16 Blds[2][64 * 64];
  const int t = threadIdx.x;
  const int lane = t & 63;
  const int g = lane >> 4;
  const int w = t >> 6;
  const int n0 = blockIdx.x * 64;
  const int b = n0 / Vv;
  const int vb = n0 % Vv;
  const int Kp = nsteps * 64;
  const int cmask = (1 << shiftC) - 1;
  const size_t plane = 2097152;

  f32x4 acc[FT / 16] = {};

  auto stage = [&](int buf, int s) {
    const int q0 = s * 64;
    char* A = (char*)&Alds[buf][0];
    char* B = (char*)&Blds[buf][0];
#pragma unroll
    for (int j = 0; j < FT / 32; ++j) {
      const int ch = j * 256 + t;
      const int f = ch >> 3, c8 = ch & 7;
      gload_lds16((const char*)Wp + ((size_t)f * Kp + q0) * 2 + ((c8 ^ (f & 7)) << 4),
                  A + ch * 16);
    }
#pragma unroll
    for (int j = 0; j < 2; ++j) {
      const int ch = j * 256 + t;
      const int q = ch >> 3, c8 = ch & 7;
      const int qq = q0 + q;
      const int k = qq >> shiftC, c = qq & cmask;
      const int sz = (q >> 3) & 7;
      gload_lds16((const char*)XS + ((size_t)k * plane + (size_t)(c * 32 + b) * Vv + vb) * 2 +
                      ((c8 ^ sz) << 4),
                  B + ch * 16);
    }
  };

  stage(0, 0);

  for (int s = 0; s < nsteps; ++s) {
    const int cur = s & 1;
    if (s + 1 < nsteps) {
      stage(cur ^ 1, s + 1);
      if constexpr (FT == 64) {
        asm volatile("s_waitcnt vmcnt(4)" ::: "memory");
      } else {
        asm volatile("s_waitcnt vmcnt(6)" ::: "memory");
      }
    } else {
      asm volatile("s_waitcnt vmcnt(0)" ::: "memory");
    }
    asm volatile("s_barrier" ::: "memory");
    const _Float16* A = &Alds[cur][0];
    const _Float16* B = &Blds[cur][0];
#pragma unroll
    for (int kk = 0; kk < 2; ++kk) {
      half8 bf;
      const int c = lane & 15;
#pragma unroll
      for (int j = 0; j < 8; ++j) {
        const int q = kk * 32 + g * 8 + j;
        const int sz = (q >> 3) & 7;
        bf[j] = B[q * 64 + ((w * 16 + c) ^ (sz << 3))];
      }
#pragma unroll
      for (int mi = 0; mi < FT / 16; ++mi) {
        const int ar = mi * 16 + c;
        half8 af = *(const half8*)((const char*)A + ar * 128 +
                                   ((kk * 64 + g * 16) ^ ((ar & 7) << 4)));
        acc[mi] = __builtin_amdgcn_mfma_f32_16x16x32_f16(af, bf, acc[mi], 0, 0, 0);
      }
    }
    asm volatile("s_barrier" ::: "memory");
  }

  const int n = n0 + w * 16 + (lane & 15);
#pragma unroll
  for (int mi = 0; mi < FT / 16; ++mi) {
#pragma unroll
    for (int r = 0; r < 4; ++r) {
      const int f = mi * 16 + g * 4 + r;
      Yt[(size_t)f * Ntot + n] = fmaxf(ascale * acc[mi][r] + bscale * bias[f], 0.f);
    }
  }
}

// ---------------- pool1 ----------------
__global__ __launch_bounds__(256) void k_pool1(const float* __restrict__ Yt,
                                               _Float16* __restrict__ X2) {
  const int idx = blockIdx.x * 256 + threadIdx.x;
  const int v2 = idx & 1023;
  const int rest = idx >> 10;
  const int b = rest & 31;
  const int f = rest >> 5;
  f32x4 q = *(const f32x4*)(Yt + (size_t)f * 131072 + b * 4096 + v2 * 4);
  float mx = fmaxf(fmaxf(q[0], q[1]), fmaxf(q[2], q[3]));
  X2[(size_t)(f * 32 + b) * 1024 + v2] = (_Float16)(mx * 0.015625f);
}

// ---------------- pool2 ----------------
__global__ __launch_bounds__(256) void k_pool2(const float* __restrict__ Yt,
                                               float* __restrict__ p2) {
  const int idx = blockIdx.x * 256 + threadIdx.x;
  const int v3 = idx & 255;
  const int rest = idx >> 8;
  const int f = rest & 127;
  const int b = rest >> 7;
  f32x4 q = *(const f32x4*)(Yt + (size_t)f * 32768 + b * 1024 + v3 * 4);
  float mx = fmaxf(fmaxf(q[0], q[1]), fmaxf(q[2], q[3]));
  p2[(size_t)b * 32768 + f * 256 + v3] = mx;
}

// ---------------- FC pass 1 ----------------
__global__ __launch_bounds__(256) void k_fc_part(const float* __restrict__ p2,
                                                 const float* __restrict__ Wfc,
                                                 float* __restrict__ partF) {
  const int b = blockIdx.x >> 3;
  const int seg = blockIdx.x & 7;
  const int t = threadIdx.x;
  const int lane = t & 63;
  const int w = t >> 6;
  const int base = seg * 4096;
  float acc[10];
#pragma unroll
  for (int o = 0; o < 10; ++o) acc[o] = 0.f;
  const float* pb = p2 + (size_t)b * 32768 + base;
  for (int i = t; i < 4096; i += 256) {
    float p = pb[i];
#pragma unroll
    for (int o = 0; o < 10; ++o) acc[o] += p * Wfc[(size_t)o * 32768 + base + i];
  }
#pragma unroll
  for (int off = 32; off > 0; off >>= 1)
#pragma unroll
    for (int o = 0; o < 10; ++o) acc[o] += __shfl_down(acc[o], off);
  __shared__ float rws[10][4];
  if (lane == 0) {
#pragma unroll
    for (int o = 0; o < 10; ++o) rws[o][w] = acc[o];
  }
  __syncthreads();
  if (t < 10) partF[blockIdx.x * 10 + t] =
      rws[t][0] + rws[t][1] + rws[t][2] + rws[t][3];
}

// ---------------- FC pass 2 ----------------
__global__ void k_fc_final(const float* __restrict__ partF,
                           const float* __restrict__ bfc,
                           float* __restrict__ out) {
  const int t = threadIdx.x;
  if (t < 320) {
    const int b = t / 10, o = t - b * 10;
    float s = 0.f;
#pragma unroll
    for (int seg = 0; seg < 8; ++seg) s += partF[(b * 8 + seg) * 10 + o];
    out[b * 10 + o] = 64.f * s + bfc[o];
  }
}

extern "C" void kernel_launch(void* const* d_in, const int* in_sizes, int n_in,
                              void* d_out, int out_size, void* d_ws, size_t ws_size,
                              hipStream_t stream) {
  (void)in_sizes; (void)n_in; (void)out_size; (void)ws_size;
  const float* x = (const float*)d_in[0];
  const int* perm = (const int*)d_in[1];
  const float* L1 = (const float*)d_in[2];
  const float* L2 = (const float*)d_in[3];
  const float* W1 = (const float*)d_in[4];
  const float* b1 = (const float*)d_in[5];
  const float* W2 = (const float*)d_in[6];
  const float* b2 = (const float*)d_in[7];
  const float* Wfc = (const float*)d_in[8];
  const float* bfc = (const float*)d_in[9];
  float* out = (float*)d_out;

  char* ws = (char*)d_ws;
  size_t off = 0;
  auto alloc = [&](size_t bytes) {
    char* p = ws + off;
    off += (bytes + 255) & ~(size_t)255;
    return p;
  };
  _Float16* L1h = (_Float16*)alloc(16777216ull * 2);
  _Float16* L2h = (_Float16*)alloc(1048576ull * 2);
  _Float16* W1p = (_Float16*)alloc(64ull * 448 * 2);
  _Float16* W2p = (_Float16*)alloc(128ull * 1664 * 2);
  float* part = (float*)alloc(256 * 4);
  float* musig = (float*)alloc(32 * 4);
  float* partF = (float*)alloc(2560 * 4);
  _Float16* XS = (_Float16*)alloc(28ull * 2097152 * 2);   // 25 states + 3 zero planes
  float* Yt = (float*)alloc(64ull * 131072 * 4);          // 32MB; aliased as Pq during convs
  float* p2 = (float*)alloc(32ull * 128 * 256 * 4);
  _Float16* Pq = (_Float16*)Yt;  // 4 partial planes (16MB), dead before dense writes Yt

  const size_t plane = 2097152;

  k_cvt_f16<<<16384, 256, 0, stream>>>(L1, L1h, 16777216);
  k_cvt_f16<<<1024, 256, 0, stream>>>(L2, L2h, 1048576);
  k_prep_w<<<112, 256, 0, stream>>>(W1, W1p, 64, 4, 28);
  k_prep_w<<<832, 256, 0, stream>>>(W2, W2p, 128, 6, 26);
  k_zero<<<3072, 256, 0, stream>>>(XS + 25 * plane, 786432);
  k_bn_partial<<<128, 256, 0, stream>>>(x, part);
  k_bn_final<<<1, 64, 0, stream>>>(part, musig);
  k_build_x0<<<8192, 256, 0, stream>>>(x, perm, musig, XS);

  // conv1: 24 recurrence steps, grid 256 = bx16 x by4 x kq4, NT=16
  for (int k = 1; k < 25; ++k) {
    k_cheb8<<<256, 512, 0, stream>>>(XS + (size_t)(k - 1) * plane, L1h, Pq, 4096, 16, 4, 2);
    k_cheb_red4<<<1024, 256, 0, stream>>>(
        Pq, XS + (size_t)(k >= 2 ? k - 2 : 0) * plane, XS + (size_t)k * plane,
        (k == 1) ? 1.f : 2.f, (k == 1) ? 0.f : 1.f);
  }
  k_dense<64><<<dim3(2048, 1), 256, 0, stream>>>(W1p, XS, b1, Yt, 4096, 4, 7,
                                                 131072, 16.f, 1.f);
  k_pool1<<<8192, 256, 0, stream>>>(Yt, XS);
  // conv2: grid 256 = bx4 x by16 x kq4, NT=4
  for (int k = 1; k < 25; ++k) {
    k_cheb8<<<256, 512, 0, stream>>>(XS + (size_t)(k - 1) * plane, L2h, Pq, 1024, 4, 2, 4);
    k_cheb_red4<<<1024, 256, 0, stream>>>(
        Pq, XS + (size_t)(k >= 2 ? k - 2 : 0) * plane, XS + (size_t)k * plane,
        (k == 1) ? 1.f : 2.f, (k == 1) ? 0.f : 1.f);
  }
  k_dense<128><<<dim3(512, 1), 256, 0, stream>>>(W2p, XS, b2, Yt, 1024, 6, 26,
                                                 32768, 1.f, 0.015625f);
  k_pool2<<<4096, 256, 0, stream>>>(Yt, p2);
  k_fc_part<<<256, 256, 0, stream>>>(p2, Wfc, partF);
  k_fc_final<<<1, 320, 0, stream>>>(partF, bfc, out);
}

// Round 8
// 1146.777 us; speedup vs baseline: 1.1184x; 1.0884x over previous
//
#include <hip/hip_runtime.h>

typedef _Float16 half8 __attribute__((ext_vector_type(8)));
typedef _Float16 half4 __attribute__((ext_vector_type(4)));
typedef float f32x4 __attribute__((ext_vector_type(4)));

__device__ __forceinline__ void gload_lds16(const void* g, void* l) {
  __builtin_amdgcn_global_load_lds((const __attribute__((address_space(1))) void*)g,
                                   (__attribute__((address_space(3))) void*)l, 16, 0, 0);
}

// ---------------- BN partial sums: grid 128 = (seg<<4 | c) ----------------
__global__ __launch_bounds__(256) void k_bn_partial(const float* __restrict__ x,
                                                    float* __restrict__ part) {
  const int c = blockIdx.x & 15;
  const int seg = blockIdx.x >> 4;
  const int t = threadIdx.x;
  float s = 0.f, s2 = 0.f;
  for (int b = 0; b < 32; ++b) {
    const float* row = x + (size_t)(b * 16 + c) * 4000 + seg * 500;
    for (int v = t; v < 500; v += 256) {
      float val = row[v];
      s += val;
      s2 += val * val;
    }
  }
#pragma unroll
  for (int off = 32; off > 0; off >>= 1) {
    s += __shfl_down(s, off);
    s2 += __shfl_down(s2, off);
  }
  __shared__ float rs_[4], rs2_[4];
  if ((t & 63) == 0) { rs_[t >> 6] = s; rs2_[t >> 6] = s2; }
  __syncthreads();
  if (t == 0) {
    part[c * 8 + seg] = rs_[0] + rs_[1] + rs_[2] + rs_[3];
    part[128 + c * 8 + seg] = rs2_[0] + rs2_[1] + rs2_[2] + rs2_[3];
  }
}

// ---------------- BN finalize ----------------
__global__ void k_bn_final(const float* __restrict__ part, float* __restrict__ musig) {
  const int c = threadIdx.x;
  if (c < 16) {
    float S = 0.f, S2 = 0.f;
#pragma unroll
    for (int seg = 0; seg < 8; ++seg) {
      S += part[c * 8 + seg];
      S2 += part[128 + c * 8 + seg];
    }
    const float inv = 1.f / 128000.f;
    float mu = S * inv;
    float var = S2 * inv - mu * mu;
    musig[c] = mu;
    musig[16 + c] = rsqrtf(var + 1e-5f);
  }
}

// ---------------- build x0 (normalized, permuted, transposed, scaled 1/16) ----------------
__global__ __launch_bounds__(256) void k_build_x0(const float* __restrict__ x,
                                                  const int* __restrict__ perm,
                                                  const float* __restrict__ musig,
                                                  _Float16* __restrict__ X0) {
  const int idx = blockIdx.x * 256 + threadIdx.x;
  const int v = idx & 4095;
  const int m = idx >> 12;
  const int b = m & 31;
  const int c = m >> 5;
  const int pv = perm[v];
  float val = 0.f;
  if (pv < 4000)
    val = (x[((size_t)(b * 16 + c)) * 4000 + pv] - musig[c]) * musig[16 + c] * 0.0625f;
  X0[idx] = (_Float16)val;
}

// ---------------- f32 -> f16 convert ----------------
__global__ __launch_bounds__(256) void k_cvt_f16(const float* __restrict__ s,
                                                 _Float16* __restrict__ d, int n) {
  const int i = (blockIdx.x * 256 + threadIdx.x) * 4;
  if (i >= n) return;
  f32x4 v = *(const f32x4*)(s + i);
  half4 h;
  h[0] = (_Float16)v[0]; h[1] = (_Float16)v[1];
  h[2] = (_Float16)v[2]; h[3] = (_Float16)v[3];
  *(half4*)(d + i) = h;
}

// ---------------- zero fill ----------------
__global__ __launch_bounds__(256) void k_zero(_Float16* __restrict__ p, int n8) {
  const int i = blockIdx.x * 256 + threadIdx.x;
  if (i < n8) *(half8*)(p + (size_t)i * 8) = half8{};
}

// ---------------- W permute+pad: Wp[f][k*CS + c] = W[f][c*25 + k] ----------------
__global__ __launch_bounds__(256) void k_prep_w(const float* __restrict__ W,
                                                _Float16* __restrict__ Wp,
                                                int F, int shiftC, int kround) {
  const int idx = blockIdx.x * 256 + threadIdx.x;
  const int CS = 1 << shiftC;
  const int KPtot = kround * CS;
  if (idx >= F * KPtot) return;
  const int f = idx / KPtot;
  const int rem = idx - f * KPtot;
  const int k = rem >> shiftC;
  const int c = rem & (CS - 1);
  float v = 0.f;
  if (k < 25) v = W[(size_t)f * (CS * 25) + c * 25 + k];
  Wp[idx] = (_Float16)v;
}

// ---------------- Chebyshev conv1 partial GEMM (R6, unchanged) ----------------
// P[kq][m][v] = sum_{u in kq K-slice} Xprev[m][u] * L[v][u]
// Tile 128m x 256v, BK=64, 512 thr = 8 waves (2m x 4v), wave 64x64 (4x4).
// 3-buffer LDS, 2-ahead staging, fine phases, counted vmcnt(6).
__global__ __launch_bounds__(512, 1) void k_cheb8(const _Float16* __restrict__ Xprev,
                                                  const _Float16* __restrict__ Lm,
                                                  _Float16* __restrict__ P,
                                                  int V, int NT, int bxbits, int bybits) {
  __shared__ _Float16 lds[3][24576];  // [buf][A:128x64 (16KB) | B:256x64 (32KB)]
  const int t = threadIdx.x;
  const int lane = t & 63;
  const int ln = lane & 15;
  const int g = lane >> 4;
  const int g16 = g << 4;
  const int w = t >> 6;
  const int wm = w >> 2, wn = w & 3;
  const int bid = blockIdx.x;
  const int bx = bid & ((1 << bxbits) - 1);
  const int by = (bid >> bxbits) & ((1 << bybits) - 1);
  const int kq = bid >> (bxbits + bybits);
  const int v0 = bx * 256, m0 = by * 128;
  const size_t rs = (size_t)V * 2;
  const int koffB = kq * NT * 128;

  const char* Ag = (const char*)Xprev + (size_t)m0 * rs + koffB;
  const char* Bg = (const char*)Lm + (size_t)v0 * rs + koffB;

  f32x4 acc[4][4] = {};

  auto stageHalf = [&](int buf, int tt, int half) {  // 3 gload_lds / thread
    char* Lb = (char*)&lds[buf][0];
#pragma unroll
    for (int j = 0; j < 3; ++j) {
      const int idx = half * 1536 + j * 512 + t;
      if (idx < 1024) {
        const int row = idx >> 3, c8 = idx & 7;
        gload_lds16(Ag + (size_t)row * rs + tt * 128 + ((c8 ^ (row & 7)) << 4),
                    Lb + idx * 16);
      } else {
        const int bi = idx - 1024;
        const int row = bi >> 3, c8 = bi & 7;
        gload_lds16(Bg + (size_t)row * rs + tt * 128 + ((c8 ^ (row & 7)) << 4),
                    Lb + 16384 + bi * 16);
      }
    }
  };

  stageHalf(0, 0, 0); stageHalf(0, 0, 1);
  stageHalf(1, 1, 0); stageHalf(1, 1, 1);
  asm volatile("s_waitcnt vmcnt(6)" ::: "memory");
  asm volatile("s_barrier" ::: "memory");

  for (int tt = 0; tt < NT; ++tt) {
    const int cur = tt % 3;
    const int nxt = (tt + 2) % 3;
    const char* A = (const char*)&lds[cur][0];
    const char* B = A + 16384;
#pragma unroll
    for (int kk = 0; kk < 2; ++kk) {
      half8 a[4], b[4];
#pragma unroll
      for (int mi = 0; mi < 4; ++mi) {
        const int ar = wm * 64 + mi * 16 + ln;
        a[mi] = *(const half8*)(A + ar * 128 + ((kk * 64 + g16) ^ ((ar & 7) << 4)));
      }
#pragma unroll
      for (int ni = 0; ni < 4; ++ni) {
        const int br = wn * 64 + ni * 16 + ln;
        b[ni] = *(const half8*)(B + br * 128 + ((kk * 64 + g16) ^ ((br & 7) << 4)));
      }
      if (tt + 2 < NT) stageHalf(nxt, tt + 2, kk);
      if (kk == 1) {
        if (tt + 2 < NT) {
          asm volatile("s_waitcnt vmcnt(6)" ::: "memory");
        } else {
          asm volatile("s_waitcnt vmcnt(0)" ::: "memory");
        }
      }
      asm volatile("s_barrier" ::: "memory");
      asm volatile("s_waitcnt lgkmcnt(0)" ::: "memory");
      __builtin_amdgcn_sched_barrier(0);
      __builtin_amdgcn_s_setprio(1);
#pragma unroll
      for (int mi = 0; mi < 4; ++mi)
#pragma unroll
        for (int ni = 0; ni < 4; ++ni)
          acc[mi][ni] = __builtin_amdgcn_mfma_f32_16x16x32_f16(a[mi], b[ni], acc[mi][ni], 0, 0, 0);
      __builtin_amdgcn_s_setprio(0);
      asm volatile("s_barrier" ::: "memory");
    }
  }

  _Float16* Pq = P + (size_t)kq * 2097152;
#pragma unroll
  for (int mi = 0; mi < 4; ++mi) {
#pragma unroll
    for (int ni = 0; ni < 4; ++ni) {
      const int vv = v0 + wn * 64 + ni * 16 + ln;
      const int mmb = m0 + wm * 64 + mi * 16 + g * 4;
#pragma unroll
      for (int r = 0; r < 4; ++r)
        Pq[(size_t)(mmb + r) * V + vv] = (_Float16)acc[mi][ni][r];
    }
  }
}

// ---------------- reduce 4 partials: Xout = alpha*(P0+..+P3) - beta*Xm2 ----------------
__global__ __launch_bounds__(256) void k_cheb_red4(const _Float16* __restrict__ P,
                                                   const _Float16* __restrict__ Xm2,
                                                   _Float16* __restrict__ Xout,
                                                   float alpha, float beta) {
  const size_t i = ((size_t)blockIdx.x * 256 + threadIdx.x) * 8;
  float s[8] = {};
#pragma unroll
  for (int p = 0; p < 4; ++p) {
    half8 v = *(const half8*)(P + (size_t)p * 2097152 + i);
#pragma unroll
    for (int j = 0; j < 8; ++j) s[j] += (float)v[j];
  }
  half8 xm2 = {};
  if (beta != 0.f) xm2 = *(const half8*)(Xm2 + i);
  half8 o;
#pragma unroll
  for (int j = 0; j < 8; ++j) o[j] = (_Float16)(alpha * s[j] - beta * (float)xm2[j]);
  *(half8*)(Xout + i) = o;
}

// ---------------- Chebyshev conv2: fused full-K GEMM, no partials ----------------
// Xout[m][v] = alpha * sum_u Xprev[m][u]*L[v][u] - beta*Xm2[m][v]
// M=2048, V=1024, K=1024. Tile 64m x 64v, BK=64, NT=16. 256 thr = 4 waves (2x2),
// wave 32x32 (2x2 frags). 3-buf LDS (48KB), 2 blocks/CU, 2-ahead staging,
// counted vmcnt(4), one phase per K-tile. Grid 512 = by32 x bx16 (bx fastest:
// per-XCD B footprint 256KB, L2-resident).
__global__ __launch_bounds__(256, 2) void k_cheb2(const _Float16* __restrict__ Xprev,
                                                  const _Float16* __restrict__ Lm,
                                                  const _Float16* __restrict__ Xm2,
                                                  _Float16* __restrict__ Xout,
                                                  float alpha, float beta) {
  __shared__ _Float16 lds[3][8192];  // [buf][A:64x64 (8KB) | B:64x64 (8KB)]
  const int t = threadIdx.x;
  const int lane = t & 63;
  const int ln = lane & 15;
  const int g = lane >> 4;
  const int g16 = g << 4;
  const int w = t >> 6;
  const int wm = w >> 1, wn = w & 1;
  const int bx = blockIdx.x & 15;
  const int by = blockIdx.x >> 4;
  const int v0 = bx * 64, m0 = by * 64;
  const size_t rs = 2048;  // 1024 * 2B

  const char* Ag = (const char*)Xprev + (size_t)m0 * rs;
  const char* Bg = (const char*)Lm + (size_t)v0 * rs;

  f32x4 acc[2][2] = {};

  auto stageHalf = [&](int buf, int tt, int half) {  // 2 gload_lds / thread
    const char* src = (half == 0) ? Ag : Bg;
    char* dst0 = (char*)&lds[buf][0] + half * 8192;
#pragma unroll
    for (int j = 0; j < 2; ++j) {
      const int idx = j * 256 + t;  // 0..511 chunks of this matrix tile
      const int row = idx >> 3, c8 = idx & 7;
      gload_lds16(src + (size_t)row * rs + tt * 128 + ((c8 ^ (row & 7)) << 4),
                  dst0 + idx * 16);
    }
  };

  // prologue: stage T0, T1 (4 loads each); wait own T0 (4 newest = T1)
  stageHalf(0, 0, 0); stageHalf(0, 0, 1);
  stageHalf(1, 1, 0); stageHalf(1, 1, 1);
  asm volatile("s_waitcnt vmcnt(4)" ::: "memory");
  asm volatile("s_barrier" ::: "memory");

  for (int tt = 0; tt < 16; ++tt) {
    const int cur = tt % 3;
    const int nxt = (tt + 2) % 3;
    const char* A = (const char*)&lds[cur][0];
    const char* B = A + 8192;
    half8 a[2][2], b[2][2];
#pragma unroll
    for (int kk = 0; kk < 2; ++kk) {
#pragma unroll
      for (int mi = 0; mi < 2; ++mi) {
        const int ar = wm * 32 + mi * 16 + ln;
        a[kk][mi] = *(const half8*)(A + ar * 128 + ((kk * 64 + g16) ^ ((ar & 7) << 4)));
      }
#pragma unroll
      for (int ni = 0; ni < 2; ++ni) {
        const int br = wn * 32 + ni * 16 + ln;
        b[kk][ni] = *(const half8*)(B + br * 128 + ((kk * 64 + g16) ^ ((br & 7) << 4)));
      }
    }
    if (tt + 2 < 16) {
      stageHalf(nxt, tt + 2, 0);
      stageHalf(nxt, tt + 2, 1);
      asm volatile("s_waitcnt vmcnt(4)" ::: "memory");  // T(t+1) landed, T(t+2) in flight
    } else {
      asm volatile("s_waitcnt vmcnt(0)" ::: "memory");
    }
    asm volatile("s_barrier" ::: "memory");
    asm volatile("s_waitcnt lgkmcnt(0)" ::: "memory");
    __builtin_amdgcn_sched_barrier(0);
    __builtin_amdgcn_s_setprio(1);
#pragma unroll
    for (int kk = 0; kk < 2; ++kk)
#pragma unroll
      for (int mi = 0; mi < 2; ++mi)
#pragma unroll
        for (int ni = 0; ni < 2; ++ni)
          acc[mi][ni] = __builtin_amdgcn_mfma_f32_16x16x32_f16(a[kk][mi], b[kk][ni],
                                                               acc[mi][ni], 0, 0, 0);
    __builtin_amdgcn_s_setprio(0);
    asm volatile("s_barrier" ::: "memory");
  }

  // fused epilogue: Xout = alpha*acc - beta*Xm2
#pragma unroll
  for (int mi = 0; mi < 2; ++mi) {
#pragma unroll
    for (int ni = 0; ni < 2; ++ni) {
      const int vv = v0 + wn * 32 + ni * 16 + ln;
      const int mmb = m0 + wm * 32 + mi * 16 + g * 4;
#pragma unroll
      for (int r = 0; r < 4; ++r) {
        const size_t idx = (size_t)(mmb + r) * 1024 + vv;
        float val = alpha * acc[mi][ni][r];
        if (beta != 0.f) val -= (float)Xm2[idx];
        Xout[idx] = (_Float16)val;
      }
    }
  }
}

// ---------------- Dense projection GEMM, gload_lds + counted vmcnt ----------------
template <int FT>
__global__ __launch_bounds__(256, 2) void k_dense(const _Float16* __restrict__ Wp,
                                                  const _Float16* __restrict__ XS,
                                                  const float* __restrict__ bias,
                                                  float* __restrict__ Yt,
                                                  int Vv, int shiftC, int nsteps,
                                                  int Ntot, float ascale, float bscale) {
  __shared__ _Float16 Alds[2][FT * 64];
  __shared__ _Float16 Blds[2][64 * 64];
  const int t = threadIdx.x;
  const int lane = t & 63;
  const int g = lane >> 4;
  const int w = t >> 6;
  const int n0 = blockIdx.x * 64;
  const int b = n0 / Vv;
  const int vb = n0 % Vv;
  const int Kp = nsteps * 64;
  const int cmask = (1 << shiftC) - 1;
  const size_t plane = 2097152;

  f32x4 acc[FT / 16] = {};

  auto stage = [&](int buf, int s) {
    const int q0 = s * 64;
    char* A = (char*)&Alds[buf][0];
    char* B = (char*)&Blds[buf][0];
#pragma unroll
    for (int j = 0; j < FT / 32; ++j) {
      const int ch = j * 256 + t;
      const int f = ch >> 3, c8 = ch & 7;
      gload_lds16((const char*)Wp + ((size_t)f * Kp + q0) * 2 + ((c8 ^ (f & 7)) << 4),
                  A + ch * 16);
    }
#pragma unroll
    for (int j = 0; j < 2; ++j) {
      const int ch = j * 256 + t;
      const int q = ch >> 3, c8 = ch & 7;
      const int qq = q0 + q;
      const int k = qq >> shiftC, c = qq & cmask;
      const int sz = (q >> 3) & 7;
      gload_lds16((const char*)XS + ((size_t)k * plane + (size_t)(c * 32 + b) * Vv + vb) * 2 +
                      ((c8 ^ sz) << 4),
                  B + ch * 16);
    }
  };

  stage(0, 0);

  for (int s = 0; s < nsteps; ++s) {
    const int cur = s & 1;
    if (s + 1 < nsteps) {
      stage(cur ^ 1, s + 1);
      if constexpr (FT == 64) {
        asm volatile("s_waitcnt vmcnt(4)" ::: "memory");
      } else {
        asm volatile("s_waitcnt vmcnt(6)" ::: "memory");
      }
    } else {
      asm volatile("s_waitcnt vmcnt(0)" ::: "memory");
    }
    asm volatile("s_barrier" ::: "memory");
    const _Float16* A = &Alds[cur][0];
    const _Float16* B = &Blds[cur][0];
#pragma unroll
    for (int kk = 0; kk < 2; ++kk) {
      half8 bf;
      const int c = lane & 15;
#pragma unroll
      for (int j = 0; j < 8; ++j) {
        const int q = kk * 32 + g * 8 + j;
        const int sz = (q >> 3) & 7;
        bf[j] = B[q * 64 + ((w * 16 + c) ^ (sz << 3))];
      }
#pragma unroll
      for (int mi = 0; mi < FT / 16; ++mi) {
        const int ar = mi * 16 + c;
        half8 af = *(const half8*)((const char*)A + ar * 128 +
                                   ((kk * 64 + g * 16) ^ ((ar & 7) << 4)));
        acc[mi] = __builtin_amdgcn_mfma_f32_16x16x32_f16(af, bf, acc[mi], 0, 0, 0);
      }
    }
    asm volatile("s_barrier" ::: "memory");
  }

  const int n = n0 + w * 16 + (lane & 15);
#pragma unroll
  for (int mi = 0; mi < FT / 16; ++mi) {
#pragma unroll
    for (int r = 0; r < 4; ++r) {
      const int f = mi * 16 + g * 4 + r;
      Yt[(size_t)f * Ntot + n] = fmaxf(ascale * acc[mi][r] + bscale * bias[f], 0.f);
    }
  }
}

// ---------------- pool1 ----------------
__global__ __launch_bounds__(256) void k_pool1(const float* __restrict__ Yt,
                                               _Float16* __restrict__ X2) {
  const int idx = blockIdx.x * 256 + threadIdx.x;
  const int v2 = idx & 1023;
  const int rest = idx >> 10;
  const int b = rest & 31;
  const int f = rest >> 5;
  f32x4 q = *(const f32x4*)(Yt + (size_t)f * 131072 + b * 4096 + v2 * 4);
  float mx = fmaxf(fmaxf(q[0], q[1]), fmaxf(q[2], q[3]));
  X2[(size_t)(f * 32 + b) * 1024 + v2] = (_Float16)(mx * 0.015625f);
}

// ---------------- pool2 ----------------
__global__ __launch_bounds__(256) void k_pool2(const float* __restrict__ Yt,
                                               float* __restrict__ p2) {
  const int idx = blockIdx.x * 256 + threadIdx.x;
  const int v3 = idx & 255;
  const int rest = idx >> 8;
  const int f = rest & 127;
  const int b = rest >> 7;
  f32x4 q = *(const f32x4*)(Yt + (size_t)f * 32768 + b * 1024 + v3 * 4);
  float mx = fmaxf(fmaxf(q[0], q[1]), fmaxf(q[2], q[3]));
  p2[(size_t)b * 32768 + f * 256 + v3] = mx;
}

// ---------------- FC pass 1 ----------------
__global__ __launch_bounds__(256) void k_fc_part(const float* __restrict__ p2,
                                                 const float* __restrict__ Wfc,
                                                 float* __restrict__ partF) {
  const int b = blockIdx.x >> 3;
  const int seg = blockIdx.x & 7;
  const int t = threadIdx.x;
  const int lane = t & 63;
  const int w = t >> 6;
  const int base = seg * 4096;
  float acc[10];
#pragma unroll
  for (int o = 0; o < 10; ++o) acc[o] = 0.f;
  const float* pb = p2 + (size_t)b * 32768 + base;
  for (int i = t; i < 4096; i += 256) {
    float p = pb[i];
#pragma unroll
    for (int o = 0; o < 10; ++o) acc[o] += p * Wfc[(size_t)o * 32768 + base + i];
  }
#pragma unroll
  for (int off = 32; off > 0; off >>= 1)
#pragma unroll
    for (int o = 0; o < 10; ++o) acc[o] += __shfl_down(acc[o], off);
  __shared__ float rws[10][4];
  if (lane == 0) {
#pragma unroll
    for (int o = 0; o < 10; ++o) rws[o][w] = acc[o];
  }
  __syncthreads();
  if (t < 10) partF[blockIdx.x * 10 + t] =
      rws[t][0] + rws[t][1] + rws[t][2] + rws[t][3];
}

// ---------------- FC pass 2 ----------------
__global__ void k_fc_final(const float* __restrict__ partF,
                           const float* __restrict__ bfc,
                           float* __restrict__ out) {
  const int t = threadIdx.x;
  if (t < 320) {
    const int b = t / 10, o = t - b * 10;
    float s = 0.f;
#pragma unroll
    for (int seg = 0; seg < 8; ++seg) s += partF[(b * 8 + seg) * 10 + o];
    out[b * 10 + o] = 64.f * s + bfc[o];
  }
}

extern "C" void kernel_launch(void* const* d_in, const int* in_sizes, int n_in,
                              void* d_out, int out_size, void* d_ws, size_t ws_size,
                              hipStream_t stream) {
  (void)in_sizes; (void)n_in; (void)out_size; (void)ws_size;
  const float* x = (const float*)d_in[0];
  const int* perm = (const int*)d_in[1];
  const float* L1 = (const float*)d_in[2];
  const float* L2 = (const float*)d_in[3];
  const float* W1 = (const float*)d_in[4];
  const float* b1 = (const float*)d_in[5];
  const float* W2 = (const float*)d_in[6];
  const float* b2 = (const float*)d_in[7];
  const float* Wfc = (const float*)d_in[8];
  const float* bfc = (const float*)d_in[9];
  float* out = (float*)d_out;

  char* ws = (char*)d_ws;
  size_t off = 0;
  auto alloc = [&](size_t bytes) {
    char* p = ws + off;
    off += (bytes + 255) & ~(size_t)255;
    return p;
  };
  _Float16* L1h = (_Float16*)alloc(16777216ull * 2);
  _Float16* L2h = (_Float16*)alloc(1048576ull * 2);
  _Float16* W1p = (_Float16*)alloc(64ull * 448 * 2);
  _Float16* W2p = (_Float16*)alloc(128ull * 1664 * 2);
  float* part = (float*)alloc(256 * 4);
  float* musig = (float*)alloc(32 * 4);
  float* partF = (float*)alloc(2560 * 4);
  _Float16* XS = (_Float16*)alloc(28ull * 2097152 * 2);   // 25 states + 3 zero planes
  float* Yt = (float*)alloc(64ull * 131072 * 4);          // 32MB; aliased as Pq during conv1
  float* p2 = (float*)alloc(32ull * 128 * 256 * 4);
  _Float16* Pq = (_Float16*)Yt;  // 4 partial planes (16MB), dead before dense1 writes Yt

  const size_t plane = 2097152;

  k_cvt_f16<<<16384, 256, 0, stream>>>(L1, L1h, 16777216);
  k_cvt_f16<<<1024, 256, 0, stream>>>(L2, L2h, 1048576);
  k_prep_w<<<112, 256, 0, stream>>>(W1, W1p, 64, 4, 28);
  k_prep_w<<<832, 256, 0, stream>>>(W2, W2p, 128, 6, 26);
  k_zero<<<3072, 256, 0, stream>>>(XS + 25 * plane, 786432);
  k_bn_partial<<<128, 256, 0, stream>>>(x, part);
  k_bn_final<<<1, 64, 0, stream>>>(part, musig);
  k_build_x0<<<8192, 256, 0, stream>>>(x, perm, musig, XS);

  // conv1: 24 recurrence steps, grid 256 = bx16 x by4 x kq4, NT=16
  for (int k = 1; k < 25; ++k) {
    k_cheb8<<<256, 512, 0, stream>>>(XS + (size_t)(k - 1) * plane, L1h, Pq, 4096, 16, 4, 2);
    k_cheb_red4<<<1024, 256, 0, stream>>>(
        Pq, XS + (size_t)(k >= 2 ? k - 2 : 0) * plane, XS + (size_t)k * plane,
        (k == 1) ? 1.f : 2.f, (k == 1) ? 0.f : 1.f);
  }
  k_dense<64><<<dim3(2048, 1), 256, 0, stream>>>(W1p, XS, b1, Yt, 4096, 4, 7,
                                                 131072, 16.f, 1.f);
  k_pool1<<<8192, 256, 0, stream>>>(Yt, XS);
  // conv2: fused full-K kernel, grid 512 = by32 x bx16, 2 blocks/CU
  for (int k = 1; k < 25; ++k) {
    k_cheb2<<<512, 256, 0, stream>>>(
        XS + (size_t)(k - 1) * plane, L2h,
        XS + (size_t)(k >= 2 ? k - 2 : 0) * plane, XS + (size_t)k * plane,
        (k == 1) ? 1.f : 2.f, (k == 1) ? 0.f : 1.f);
  }
  k_dense<128><<<dim3(512, 1), 256, 0, stream>>>(W2p, XS, b2, Yt, 1024, 6, 26,
                                                 32768, 1.f, 0.015625f);
  k_pool2<<<4096, 256, 0, stream>>>(Yt, p2);
  k_fc_part<<<256, 256, 0, stream>>>(p2, Wfc, partF);
  k_fc_final<<<1, 320, 0, stream>>>(partF, bfc, out);
}